// Round 1
// baseline (98.195 us; speedup 1.0000x reference)
//
#include <hip/hip_runtime.h>
#include <hip/hip_bf16.h>
#include <math.h>

#define B_N 4096
#define D_N 1024
#define K_N 256
#define BM 16
#define BK 32

static constexpr float K_EPS = 1e-8f;

// ---------------------------------------------------------------------------
// Kernel 1: normalize centroids into ws (cn), compute datapoint inverse norms.
// grid = K_N + B_N blocks, 256 threads. Each block handles one row (D=1024).
// ---------------------------------------------------------------------------
__global__ __launch_bounds__(256) void knorm_kernel(
    const float* __restrict__ dp, const float* __restrict__ cent,
    float* __restrict__ cn, float* __restrict__ invn)
{
    int bid = blockIdx.x;
    int tid = threadIdx.x;
    bool isC = bid < K_N;
    int row = isC ? bid : bid - K_N;
    const float* src = isC ? (cent + (size_t)row * D_N) : (dp + (size_t)row * D_N);
    float4 v = reinterpret_cast<const float4*>(src)[tid];   // D/4 == 256 == blockDim
    float s = v.x * v.x + v.y * v.y + v.z * v.z + v.w * v.w;
    #pragma unroll
    for (int o = 32; o > 0; o >>= 1) s += __shfl_down(s, o);
    __shared__ float red[4];
    __shared__ float s_inv;
    if ((tid & 63) == 0) red[tid >> 6] = s;
    __syncthreads();
    if (tid == 0) {
        float t = red[0] + red[1] + red[2] + red[3];
        s_inv = 1.0f / fmaxf(sqrtf(t), K_EPS);
    }
    __syncthreads();
    float inv = s_inv;
    if (isC) {
        float4 o4 = make_float4(v.x * inv, v.y * inv, v.z * inv, v.w * inv);
        reinterpret_cast<float4*>(cn + (size_t)row * D_N)[tid] = o4;
    } else if (tid == 0) {
        invn[row] = inv;
    }
}

// ---------------------------------------------------------------------------
// Kernel 2: sims = (dp . cn^T) * invn  (f32 VALU GEMM, tile 16 rows x 256 cols)
// plus per-row top-2 (value + index) via in-wave butterfly merge.
// grid = B/16 = 256 blocks, 256 threads (4 waves; wave rg owns rows 4rg..4rg+3,
// lane lc owns cols 4lc..4lc+3). Register-prefetch staging to hide HBM latency.
// ---------------------------------------------------------------------------
__global__ __launch_bounds__(256) void kgemm_kernel(
    const float* __restrict__ dp, const float* __restrict__ cn,
    const float* __restrict__ invn,
    float* __restrict__ out_sims, float* __restrict__ out_dpidx,
    float* __restrict__ out_hnidx, float* __restrict__ out_top1,
    int* __restrict__ ws_dpidx, int* __restrict__ ws_hnidx)
{
    __shared__ float As[BK][BM];     // 2 KB, [k][m] so 4 rows are contiguous
    __shared__ float Bs[BK][K_N];    // 32 KB, [k][n] so 4 cols are contiguous
    int tid = threadIdx.x;
    int rg  = tid >> 6;              // wave id 0..3
    int lc  = tid & 63;              // lane 0..63
    int brow = blockIdx.x * BM;

    float acc[4][4] = {};

    // staging registers (issue-early / write-late)
    float4 pa;
    float4 pb[8];
    int ar = tid >> 3, akq = tid & 7;

    auto issue_loads = [&](int k0) {
        if (tid < 128)
            pa = *reinterpret_cast<const float4*>(
                &dp[(size_t)(brow + ar) * D_N + k0 + akq * 4]);
        const float4* src = reinterpret_cast<const float4*>(&cn[(size_t)tid * D_N + k0]);
        #pragma unroll
        for (int q = 0; q < 8; ++q) pb[q] = src[q];
    };

    issue_loads(0);
    for (int k0 = 0; k0 < D_N; k0 += BK) {
        if (tid < 128) {
            As[akq * 4 + 0][ar] = pa.x;
            As[akq * 4 + 1][ar] = pa.y;
            As[akq * 4 + 2][ar] = pa.z;
            As[akq * 4 + 3][ar] = pa.w;
        }
        #pragma unroll
        for (int q = 0; q < 8; ++q) {
            Bs[q * 4 + 0][tid] = pb[q].x;
            Bs[q * 4 + 1][tid] = pb[q].y;
            Bs[q * 4 + 2][tid] = pb[q].z;
            Bs[q * 4 + 3][tid] = pb[q].w;
        }
        __syncthreads();
        if (k0 + BK < D_N) issue_loads(k0 + BK);   // in flight during compute
        #pragma unroll
        for (int kk = 0; kk < BK; ++kk) {
            float4 a = *reinterpret_cast<const float4*>(&As[kk][rg * 4]);
            float4 b = *reinterpret_cast<const float4*>(&Bs[kk][lc * 4]);
            acc[0][0] += a.x * b.x; acc[0][1] += a.x * b.y; acc[0][2] += a.x * b.z; acc[0][3] += a.x * b.w;
            acc[1][0] += a.y * b.x; acc[1][1] += a.y * b.y; acc[1][2] += a.y * b.z; acc[1][3] += a.y * b.w;
            acc[2][0] += a.z * b.x; acc[2][1] += a.z * b.y; acc[2][2] += a.z * b.z; acc[2][3] += a.z * b.w;
            acc[3][0] += a.w * b.x; acc[3][1] += a.w * b.y; acc[3][2] += a.w * b.z; acc[3][3] += a.w * b.w;
        }
        __syncthreads();
    }

    int rbase = brow + rg * 4;
    #pragma unroll
    for (int i = 0; i < 4; ++i) {
        float iv = invn[rbase + i];
        #pragma unroll
        for (int j = 0; j < 4; ++j) acc[i][j] *= iv;
        float4 o4 = make_float4(acc[i][0], acc[i][1], acc[i][2], acc[i][3]);
        *reinterpret_cast<float4*>(&out_sims[(size_t)(rbase + i) * K_N + lc * 4]) = o4;
    }

    // per-row top-2 across the wave (ties -> lower index, matching jnp)
    #pragma unroll
    for (int i = 0; i < 4; ++i) {
        float v1 = acc[i][0]; int i1 = lc * 4;
        float v2 = -INFINITY; int i2 = 0;
        #pragma unroll
        for (int j = 1; j < 4; ++j) {
            float val = acc[i][j]; int idx = lc * 4 + j;
            if (val > v1) { v2 = v1; i2 = i1; v1 = val; i1 = idx; }
            else if (val > v2) { v2 = val; i2 = idx; }
        }
        #pragma unroll
        for (int o = 1; o < 64; o <<= 1) {
            float ov1 = __shfl_xor(v1, o);
            float ov2 = __shfl_xor(v2, o);
            int   oi1 = __shfl_xor(i1, o);
            int   oi2 = __shfl_xor(i2, o);
            if (ov1 > v1 || (ov1 == v1 && oi1 < i1)) {
                // other's top wins; second = better of (v1,i1) and (ov2,oi2)
                float nv2; int ni2;
                if (v1 > ov2 || (v1 == ov2 && i1 < oi2)) { nv2 = v1; ni2 = i1; }
                else { nv2 = ov2; ni2 = oi2; }
                v1 = ov1; i1 = oi1; v2 = nv2; i2 = ni2;
            } else if (ov1 > v2 || (ov1 == v2 && oi1 < i2)) {
                v2 = ov1; i2 = oi1;
            }
        }
        if (lc == 0) {
            int row = rbase + i;
            out_dpidx[row] = (float)i1;
            out_hnidx[row] = (float)i2;
            out_top1[row]  = v2;
            ws_dpidx[row]  = i1;
            ws_hnidx[row]  = i2;
        }
    }
}

// ---------------------------------------------------------------------------
// Kernel 3: all remaining outputs. grid = 2*B + K blocks:
//   [0, B)      : gather dp_centroid + hard_negative rows (float4/thread each)
//   [B, 2B)     : dp_cluster row i (16 floats/thread)
//   [2B, 2B+K)  : index_dp row k (16 floats/thread)
// ---------------------------------------------------------------------------
__global__ __launch_bounds__(256) void kout_kernel(
    const float* __restrict__ cent,
    const int* __restrict__ dpidx, const int* __restrict__ hnidx,
    float* __restrict__ out_dpcent, float* __restrict__ out_hneg,
    float* __restrict__ out_cluster, float* __restrict__ out_indexdp)
{
    int bid = blockIdx.x;
    int tid = threadIdx.x;
    if (bid < B_N) {
        int b = bid;
        int i1 = dpidx[b], i2 = hnidx[b];
        float4 v1 = reinterpret_cast<const float4*>(cent + (size_t)i1 * D_N)[tid];
        float4 v2 = reinterpret_cast<const float4*>(cent + (size_t)i2 * D_N)[tid];
        reinterpret_cast<float4*>(out_dpcent + (size_t)b * D_N)[tid] = v1;
        reinterpret_cast<float4*>(out_hneg   + (size_t)b * D_N)[tid] = v2;
    } else if (bid < 2 * B_N) {
        int i = bid - B_N;
        int me = dpidx[i];
        int j0 = tid * 16;
        float* dst = out_cluster + (size_t)i * B_N;
        #pragma unroll
        for (int q = 0; q < 4; ++q) {
            int j = j0 + q * 4;
            float4 v;
            v.x = (dpidx[j + 0] == me && (j + 0) != i) ? 1.0f : 0.0f;
            v.y = (dpidx[j + 1] == me && (j + 1) != i) ? 1.0f : 0.0f;
            v.z = (dpidx[j + 2] == me && (j + 2) != i) ? 1.0f : 0.0f;
            v.w = (dpidx[j + 3] == me && (j + 3) != i) ? 1.0f : 0.0f;
            *reinterpret_cast<float4*>(dst + j) = v;
        }
    } else {
        int k = bid - 2 * B_N;
        int j0 = tid * 16;
        float* dst = out_indexdp + (size_t)k * B_N;
        #pragma unroll
        for (int q = 0; q < 4; ++q) {
            int j = j0 + q * 4;
            float4 v;
            v.x = (dpidx[j + 0] == k) ? 1.0f : 0.0f;
            v.y = (dpidx[j + 1] == k) ? 1.0f : 0.0f;
            v.z = (dpidx[j + 2] == k) ? 1.0f : 0.0f;
            v.w = (dpidx[j + 3] == k) ? 1.0f : 0.0f;
            *reinterpret_cast<float4*>(dst + j) = v;
        }
    }
}

extern "C" void kernel_launch(void* const* d_in, const int* in_sizes, int n_in,
                              void* d_out, int out_size, void* d_ws, size_t ws_size,
                              hipStream_t stream)
{
    const float* dp   = (const float*)d_in[0];   // 4096 x 1024 f32
    const float* cent = (const float*)d_in[1];   // 256 x 1024 f32
    // d_in[2] (batch_cos_sim) is unused by the reference outputs.
    float* out = (float*)d_out;

    // output layout (element offsets, all read back as f32)
    float* o_sims   = out;                 // 4096*256
    float* o_dpidx  = out + 1048576;       // 4096
    float* o_clust  = out + 1052672;       // 4096*4096
    float* o_idxdp  = out + 17829888;      // 256*4096
    float* o_dpcent = out + 18878464;      // 4096*1024
    float* o_hneg   = out + 23072768;      // 4096*1024
    float* o_hnidx  = out + 27267072;      // 4096
    float* o_top1   = out + 27271168;      // 4096

    char* ws = (char*)d_ws;
    float* cn   = (float*)ws;                         // 1 MiB normalized centroids
    int*   widx = (int*)(ws + (1 << 20));             // 16 KiB
    int*   whn  = (int*)(ws + (1 << 20) + 16384);     // 16 KiB
    float* winv = (float*)(ws + (1 << 20) + 32768);   // 16 KiB

    hipLaunchKernelGGL(knorm_kernel, dim3(K_N + B_N), dim3(256), 0, stream,
                       dp, cent, cn, winv);
    hipLaunchKernelGGL(kgemm_kernel, dim3(B_N / BM), dim3(256), 0, stream,
                       dp, cn, winv, o_sims, o_dpidx, o_hnidx, o_top1, widx, whn);
    hipLaunchKernelGGL(kout_kernel, dim3(2 * B_N + K_N), dim3(256), 0, stream,
                       cent, widx, whn, o_dpcent, o_hneg, o_clust, o_idxdp);
}

// Round 3
// 83.744 us; speedup vs baseline: 1.1726x; 1.1726x over previous
//
#include <hip/hip_runtime.h>
#include <hip/hip_bf16.h>
#include <math.h>

#define B_N 4096
#define D_N 1024
#define K_N 256
#define SPLITS 4
#define KCHUNK 256   // D_N / SPLITS

static constexpr float K_EPS = 1e-8f;

// ---------------------------------------------------------------------------
// Kernel 1: normalize centroids into ws as TRANSPOSED cnT[D][K]; compute
// datapoint inverse norms. grid = K_N + B_N blocks, 256 threads.
// ---------------------------------------------------------------------------
__global__ __launch_bounds__(256) void knorm_kernel(
    const float* __restrict__ dp, const float* __restrict__ cent,
    float* __restrict__ cnT, float* __restrict__ invn)
{
    int bid = blockIdx.x;
    int tid = threadIdx.x;
    bool isC = bid < K_N;
    int row = isC ? bid : bid - K_N;
    const float* src = isC ? (cent + (size_t)row * D_N) : (dp + (size_t)row * D_N);
    float4 v = reinterpret_cast<const float4*>(src)[tid];   // D/4 == 256 == blockDim
    float s = v.x * v.x + v.y * v.y + v.z * v.z + v.w * v.w;
    #pragma unroll
    for (int o = 32; o > 0; o >>= 1) s += __shfl_down(s, o);
    __shared__ float red[4];
    __shared__ float s_inv;
    if ((tid & 63) == 0) red[tid >> 6] = s;
    __syncthreads();
    if (tid == 0) {
        float t = red[0] + red[1] + red[2] + red[3];
        s_inv = 1.0f / fmaxf(sqrtf(t), K_EPS);
    }
    __syncthreads();
    float inv = s_inv;
    if (isC) {
        // transposed scatter: cnT[d][k] = cn[k][d]; 1 MB total, L2 merges lines
        cnT[(size_t)(tid * 4 + 0) * K_N + row] = v.x * inv;
        cnT[(size_t)(tid * 4 + 1) * K_N + row] = v.y * inv;
        cnT[(size_t)(tid * 4 + 2) * K_N + row] = v.z * inv;
        cnT[(size_t)(tid * 4 + 3) * K_N + row] = v.w * inv;
    } else if (tid == 0) {
        invn[row] = inv;
    }
}

// ---------------------------------------------------------------------------
// Kernel 2: split-K GEMM partials, NO LDS / NO barriers.
// grid = 128 row-tiles x 4 k-splits = 512 blocks, 256 threads (4 waves).
// Wave handles 8 rows x 256 cols; lane owns 4 cols. A-operands are
// wave-uniform -> SGPR via s_load (readfirstlane-forced); B from L2-resident
// cnT[D][K] as coalesced float4. Per kk per lane: 32 FMA + 1 float4 load.
// Partials land in the dp_cluster output region (overwritten later by kout).
// ---------------------------------------------------------------------------
__global__ __launch_bounds__(256) void kgemm_kernel(
    const float* __restrict__ dp, const float* __restrict__ cnT,
    float* __restrict__ part)
{
    int tid = threadIdx.x;
    int lc  = tid & 63;
    int wr  = __builtin_amdgcn_readfirstlane(tid >> 6);   // uniform wave id
    int bx  = blockIdx.x;
    int mt  = bx & 127;        // row tile
    int s   = bx >> 7;         // k-split
    int brow  = mt * 32 + wr * 8;
    int kbase = s * KCHUNK;

    const float* arow = dp + (size_t)brow * D_N + kbase;   // uniform base
    const float4* bt  = reinterpret_cast<const float4*>(cnT + (size_t)kbase * K_N);

    float acc[8][4] = {};

    for (int k0 = 0; k0 < KCHUNK; k0 += 8) {
        float a[8][8];                 // wave-uniform -> SGPRs (s_load)
        #pragma unroll
        for (int i = 0; i < 8; ++i)
            #pragma unroll
            for (int j = 0; j < 8; ++j)
                a[i][j] = arow[(size_t)i * D_N + k0 + j];

        float4 b[8];                   // 8 independent L2 loads in flight
        #pragma unroll
        for (int j = 0; j < 8; ++j)
            b[j] = bt[(size_t)(k0 + j) * (K_N / 4) + lc];

        #pragma unroll
        for (int j = 0; j < 8; ++j)
            #pragma unroll
            for (int i = 0; i < 8; ++i) {
                acc[i][0] += a[i][j] * b[j].x;
                acc[i][1] += a[i][j] * b[j].y;
                acc[i][2] += a[i][j] * b[j].z;
                acc[i][3] += a[i][j] * b[j].w;
            }
    }

    float* pout = part + (size_t)s * (B_N * K_N);
    #pragma unroll
    for (int i = 0; i < 8; ++i) {
        float4 o4 = make_float4(acc[i][0], acc[i][1], acc[i][2], acc[i][3]);
        *reinterpret_cast<float4*>(&pout[(size_t)(brow + i) * K_N + lc * 4]) = o4;
    }
}

// ---------------------------------------------------------------------------
// Kernel 2b: sum the 4 partials, scale by invn, write sims, per-row top-2.
// grid = 1024 blocks x 256 threads; wave per row.
// ---------------------------------------------------------------------------
__global__ __launch_bounds__(256) void kreduce_kernel(
    const float* __restrict__ part, const float* __restrict__ invn,
    float* __restrict__ out_sims, float* __restrict__ out_dpidx,
    float* __restrict__ out_hnidx, float* __restrict__ out_top1,
    int* __restrict__ ws_dpidx, int* __restrict__ ws_hnidx)
{
    int tid = threadIdx.x;
    int lc  = tid & 63;
    int row = blockIdx.x * 4 + (tid >> 6);

    const float4* p = reinterpret_cast<const float4*>(part);
    size_t off = (size_t)row * (K_N / 4) + lc;
    float4 v0 = p[off];
    float4 v1 = p[off + 1 * (size_t)B_N * (K_N / 4)];
    float4 v2 = p[off + 2 * (size_t)B_N * (K_N / 4)];
    float4 v3 = p[off + 3 * (size_t)B_N * (K_N / 4)];
    float iv = invn[row];
    float c0 = (v0.x + v1.x + v2.x + v3.x) * iv;
    float c1 = (v0.y + v1.y + v2.y + v3.y) * iv;
    float c2 = (v0.z + v1.z + v2.z + v3.z) * iv;
    float c3 = (v0.w + v1.w + v2.w + v3.w) * iv;

    reinterpret_cast<float4*>(out_sims)[off] = make_float4(c0, c1, c2, c3);

    // per-row top-2 across the wave (ties -> lower index, matching jnp)
    float v1b = c0; int i1 = lc * 4;
    float v2b = -INFINITY; int i2 = 0;
    {
        float vals[3] = {c1, c2, c3};
        #pragma unroll
        for (int j = 0; j < 3; ++j) {
            float val = vals[j]; int idx = lc * 4 + j + 1;
            if (val > v1b) { v2b = v1b; i2 = i1; v1b = val; i1 = idx; }
            else if (val > v2b) { v2b = val; i2 = idx; }
        }
    }
    #pragma unroll
    for (int o = 1; o < 64; o <<= 1) {
        float ov1 = __shfl_xor(v1b, o);
        float ov2 = __shfl_xor(v2b, o);
        int   oi1 = __shfl_xor(i1, o);
        int   oi2 = __shfl_xor(i2, o);
        if (ov1 > v1b || (ov1 == v1b && oi1 < i1)) {
            float nv2; int ni2;
            if (v1b > ov2 || (v1b == ov2 && i1 < oi2)) { nv2 = v1b; ni2 = i1; }
            else { nv2 = ov2; ni2 = oi2; }
            v1b = ov1; i1 = oi1; v2b = nv2; i2 = ni2;
        } else if (ov1 > v2b || (ov1 == v2b && oi1 < i2)) {
            v2b = ov1; i2 = oi1;
        }
    }
    if (lc == 0) {
        out_dpidx[row] = (float)i1;
        out_hnidx[row] = (float)i2;
        out_top1[row]  = v2b;
        ws_dpidx[row]  = i1;
        ws_hnidx[row]  = i2;
    }
}

// ---------------------------------------------------------------------------
// Kernel 3: all remaining outputs. grid = 2*B + K blocks:
//   [0, B)      : gather dp_centroid + hard_negative rows (float4/thread each)
//   [B, 2B)     : dp_cluster row i (16 floats/thread)
//   [2B, 2B+K)  : index_dp row k (16 floats/thread)
// ---------------------------------------------------------------------------
__global__ __launch_bounds__(256) void kout_kernel(
    const float* __restrict__ cent,
    const int* __restrict__ dpidx, const int* __restrict__ hnidx,
    float* __restrict__ out_dpcent, float* __restrict__ out_hneg,
    float* __restrict__ out_cluster, float* __restrict__ out_indexdp)
{
    int bid = blockIdx.x;
    int tid = threadIdx.x;
    if (bid < B_N) {
        int b = bid;
        int i1 = dpidx[b], i2 = hnidx[b];
        float4 v1 = reinterpret_cast<const float4*>(cent + (size_t)i1 * D_N)[tid];
        float4 v2 = reinterpret_cast<const float4*>(cent + (size_t)i2 * D_N)[tid];
        reinterpret_cast<float4*>(out_dpcent + (size_t)b * D_N)[tid] = v1;
        reinterpret_cast<float4*>(out_hneg   + (size_t)b * D_N)[tid] = v2;
    } else if (bid < 2 * B_N) {
        int i = bid - B_N;
        int me = dpidx[i];
        int j0 = tid * 16;
        float* dst = out_cluster + (size_t)i * B_N;
        #pragma unroll
        for (int q = 0; q < 4; ++q) {
            int j = j0 + q * 4;
            float4 v;
            v.x = (dpidx[j + 0] == me && (j + 0) != i) ? 1.0f : 0.0f;
            v.y = (dpidx[j + 1] == me && (j + 1) != i) ? 1.0f : 0.0f;
            v.z = (dpidx[j + 2] == me && (j + 2) != i) ? 1.0f : 0.0f;
            v.w = (dpidx[j + 3] == me && (j + 3) != i) ? 1.0f : 0.0f;
            *reinterpret_cast<float4*>(dst + j) = v;
        }
    } else {
        int k = bid - 2 * B_N;
        int j0 = tid * 16;
        float* dst = out_indexdp + (size_t)k * B_N;
        #pragma unroll
        for (int q = 0; q < 4; ++q) {
            int j = j0 + q * 4;
            float4 v;
            v.x = (dpidx[j + 0] == k) ? 1.0f : 0.0f;
            v.y = (dpidx[j + 1] == k) ? 1.0f : 0.0f;
            v.z = (dpidx[j + 2] == k) ? 1.0f : 0.0f;
            v.w = (dpidx[j + 3] == k) ? 1.0f : 0.0f;
            *reinterpret_cast<float4*>(dst + j) = v;
        }
    }
}

extern "C" void kernel_launch(void* const* d_in, const int* in_sizes, int n_in,
                              void* d_out, int out_size, void* d_ws, size_t ws_size,
                              hipStream_t stream)
{
    const float* dp   = (const float*)d_in[0];   // 4096 x 1024 f32
    const float* cent = (const float*)d_in[1];   // 256 x 1024 f32
    // d_in[2] (batch_cos_sim) is unused by the reference outputs.
    float* out = (float*)d_out;

    // output layout (element offsets, all read back as f32)
    float* o_sims   = out;                 // 4096*256
    float* o_dpidx  = out + 1048576;       // 4096
    float* o_clust  = out + 1052672;       // 4096*4096  (also split-K scratch)
    float* o_idxdp  = out + 17829888;      // 256*4096
    float* o_dpcent = out + 18878464;      // 4096*1024
    float* o_hneg   = out + 23072768;      // 4096*1024
    float* o_hnidx  = out + 27267072;      // 4096
    float* o_top1   = out + 27271168;      // 4096

    char* ws = (char*)d_ws;
    float* cnT  = (float*)ws;                         // 1 MiB transposed centroids
    int*   widx = (int*)(ws + (1 << 20));             // 16 KiB
    int*   whn  = (int*)(ws + (1 << 20) + 16384);     // 16 KiB
    float* winv = (float*)(ws + (1 << 20) + 32768);   // 16 KiB

    float* part = o_clust;   // 16 MB of split-K partials, later overwritten

    hipLaunchKernelGGL(knorm_kernel, dim3(K_N + B_N), dim3(256), 0, stream,
                       dp, cent, cnT, winv);
    hipLaunchKernelGGL(kgemm_kernel, dim3(128 * SPLITS), dim3(256), 0, stream,
                       dp, cnT, part);
    hipLaunchKernelGGL(kreduce_kernel, dim3(B_N / 4), dim3(256), 0, stream,
                       part, winv, o_sims, o_dpidx, o_hnidx, o_top1, widx, whn);
    hipLaunchKernelGGL(kout_kernel, dim3(2 * B_N + K_N), dim3(256), 0, stream,
                       cent, widx, whn, o_dpcent, o_hneg, o_clust, o_idxdp);
}